// Round 7
// baseline (255.033 us; speedup 1.0000x reference)
//
#include <hip/hip_runtime.h>

#define N_PTS   2000000
#define DIM     128
#define KSEL    15
#define TPB     256
#define NBLK    2048
#define NCL     (NBLK * (TPB / 4))       // 131072 4-lane clusters, sweep stride
#define ROWS_PER_BLK ((N_PTS + NBLK - 1) / NBLK)   // 977
#define CAP     32768
#define FBIG    3.4028235e38f
#define IBIG    0x7fffffff

typedef float v4f __attribute__((ext_vector_type(4)));

// ---------------------------------------------------------------------------
// Kernel 1: distances. 4 lanes per row, 8 x float4 per lane, nontemporal
// loads (td is a 1GB dead stream — keep it out of L2). Two independent fma
// chains, 2-shfl cluster reduce. Grid-stride sweep. Block 0 also zeroes the
// cnt/done counters used by k_rest (replay-safe under 0xAA ws poison).
// ---------------------------------------------------------------------------
__global__ __launch_bounds__(TPB) void k_dist(const float* __restrict__ x,
                                              const float* __restrict__ td,
                                              float* __restrict__ d2out,
                                              float* __restrict__ bmin,
                                              int* __restrict__ cnt,
                                              int* __restrict__ done) {
  const int tid = threadIdx.x;
  if (blockIdx.x == 0 && tid == 0) { *cnt = 0; *done = 0; }

  const int c  = tid & 3;                          // lane within cluster
  const int cl = blockIdx.x * (TPB / 4) + (tid >> 2);

  const v4f* x4 = (const v4f*)x;
  v4f xv[8];
#pragma unroll
  for (int j = 0; j < 8; j++) xv[j] = x4[j * 4 + c];

  float xsq = 0.f;
#pragma unroll
  for (int j = 0; j < 8; j++)
    xsq += xv[j].x * xv[j].x + xv[j].y * xv[j].y
         + xv[j].z * xv[j].z + xv[j].w * xv[j].w;
  xsq += __shfl_xor(xsq, 1);
  xsq += __shfl_xor(xsq, 2);

  float mymin = FBIG;
#pragma unroll 2
  for (int row = cl; row < N_PTS; row += NCL) {
    const v4f* rp = (const v4f*)(td + (size_t)row * DIM);
    v4f tv[8];
#pragma unroll
    for (int j = 0; j < 8; j++) tv[j] = __builtin_nontemporal_load(rp + j * 4 + c);

    float att = 0.f, atx = 0.f;
#pragma unroll
    for (int j = 0; j < 8; j++) {
      att = fmaf(tv[j].x, tv[j].x, att);  atx = fmaf(tv[j].x, xv[j].x, atx);
      att = fmaf(tv[j].y, tv[j].y, att);  atx = fmaf(tv[j].y, xv[j].y, atx);
      att = fmaf(tv[j].z, tv[j].z, att);  atx = fmaf(tv[j].z, xv[j].z, atx);
      att = fmaf(tv[j].w, tv[j].w, att);  atx = fmaf(tv[j].w, xv[j].w, atx);
    }
    float s = fmaf(-2.f, atx, att);
    s += __shfl_xor(s, 1);
    s += __shfl_xor(s, 2);
    float d2 = fmaxf(s + xsq, 0.f);
    if (c == 0) d2out[row] = d2;
    mymin = fminf(mymin, d2);
  }

  __shared__ float smin[TPB];
  smin[tid] = mymin;
  __syncthreads();
  for (int s = TPB / 2; s > 0; s >>= 1) {
    if (tid < s) smin[tid] = fminf(smin[tid], smin[tid + s]);
    __syncthreads();
  }
  if (tid == 0) bmin[blockIdx.x] = smin[0];
}

// ---------------------------------------------------------------------------
// Kernel 2: fused tail. Each block: (1) wave 0 redundantly computes
// T = 15th-smallest block-min (identical IEEE ops in every block -> identical
// T; each block-min is a real point's d2, so count(d2<=T) >= 15); (2) compact
// the block's contiguous d2 slice via device-scope atomics; (3) last-done
// block (atomic ticket) does the exact (d2, idx)-ordered top-15 + vote.
// Ordering matches lax.top_k tie-break (lowest index) and jnp.argmax
// tie-break (smallest class). cand/cnt read back with atomic loads ->
// no cross-XCD coherence assumptions on plain stores.
// ---------------------------------------------------------------------------
__global__ __launch_bounds__(TPB) void k_rest(const float* __restrict__ bmin,
                                              const float* __restrict__ d2,
                                              const int* __restrict__ labels,
                                              int* __restrict__ cnt,
                                              int* __restrict__ done,
                                              int* __restrict__ cand,
                                              float* __restrict__ out) {
  const int tid = threadIdx.x;
  __shared__ float sT;
  __shared__ int sTicket;

  // ---- phase 1: wave 0 computes T (2048 -> 15th smallest)
  if (tid < 64) {
    float lv[KSEL];
#pragma unroll
    for (int k = 0; k < KSEL; k++) lv[k] = FBIG;
#pragma unroll
    for (int it = 0; it < NBLK / 64; it++) {       // 32 values per lane
      float v = bmin[tid + it * 64];
#pragma unroll
      for (int q = 0; q < KSEL; q++) {             // static bubble insert
        float mn = fminf(lv[q], v);
        v = fmaxf(lv[q], v);
        lv[q] = mn;
      }
    }
    float T = FBIG;
#pragma unroll 1
    for (int k = 0; k < KSEL; k++) {
      float bv = lv[0];
      int   bl = tid;
#pragma unroll
      for (int m = 1; m < 64; m <<= 1) {
        float ov = __shfl_xor(bv, m);
        int   ol = __shfl_xor(bl, m);
        if (ov < bv || (ov == bv && ol < bl)) { bv = ov; bl = ol; }
      }
      if (tid == bl) {                              // winner consumes head
#pragma unroll
        for (int q = 0; q < KSEL - 1; q++) lv[q] = lv[q + 1];
        lv[KSEL - 1] = FBIG;
      }
      T = bv;
    }
    if (tid == 0) sT = T;
  }
  __syncthreads();
  const float T = sT;

  // ---- phase 2: compact this block's contiguous slice
  const int r0 = blockIdx.x * ROWS_PER_BLK;
  int rend = r0 + ROWS_PER_BLK;
  if (rend > N_PTS) rend = N_PTS;
  for (int i = r0 + tid; i < rend; i += TPB) {
    if (d2[i] <= T) {
      int p = atomicAdd(cnt, 1);
      if (p < CAP) atomicExch(&cand[p], i);
    }
  }
  __syncthreads();                                  // drains this block's mem ops

  if (tid == 0) sTicket = atomicAdd(done, 1);
  __syncthreads();
  if (sTicket != NBLK - 1) return;

  // ---- phase 3: last block finalizes (one wave)
  if (tid >= 64) return;
  const int lane = tid;
  int n = atomicAdd(cnt, 0);
  if (n > CAP) n = CAP;

  float lv[KSEL]; int li[KSEL];
#pragma unroll
  for (int k = 0; k < KSEL; k++) { lv[k] = FBIG; li[k] = IBIG; }

  for (int cdx = lane; cdx < n; cdx += 64) {
    int vi = atomicAdd(&cand[cdx], 0);              // device-scope load
    float v = d2[vi];
    if (v < lv[KSEL - 1] || (v == lv[KSEL - 1] && vi < li[KSEL - 1])) {
#pragma unroll
      for (int q = 0; q < KSEL; q++) {              // static pair bubble insert
        bool less = (v < lv[q]) || (v == lv[q] && vi < li[q]);
        float tv = less ? lv[q] : v;  int ti = less ? li[q] : vi;
        float nv = less ? v : lv[q];  int ni = less ? vi : li[q];
        lv[q] = nv; li[q] = ni;
        v = tv; vi = ti;
      }
    }
  }

  int c0 = 0, c1 = 0, c2 = 0;
#pragma unroll 1
  for (int k = 0; k < KSEL; k++) {
    float bv = lv[0]; int bi = li[0]; int bl = lane;
#pragma unroll
    for (int m = 1; m < 64; m <<= 1) {
      float ov = __shfl_xor(bv, m);
      int   oi = __shfl_xor(bi, m);
      int   ol = __shfl_xor(bl, m);
      if (ov < bv || (ov == bv && (oi < bi || (oi == bi && ol < bl)))) {
        bv = ov; bi = oi; bl = ol;
      }
    }
    if (lane == bl) {                               // winner consumes head
#pragma unroll
      for (int q = 0; q < KSEL - 1; q++) { lv[q] = lv[q + 1]; li[q] = li[q + 1]; }
      lv[KSEL - 1] = FBIG; li[KSEL - 1] = IBIG;
    }
    if (lane == 0 && bi >= 0 && bi < N_PTS) {
      int lb = labels[bi];
      if (lb == 0) c0++; else if (lb == 1) c1++; else c2++;
    }
  }
  if (lane == 0) {
    int best = 0, bc = c0;
    if (c1 > bc) { best = 1; bc = c1; }
    if (c2 > bc) { best = 2; }
    out[0] = (float)best;
  }
}

extern "C" void kernel_launch(void* const* d_in, const int* in_sizes, int n_in,
                              void* d_out, int out_size, void* d_ws, size_t ws_size,
                              hipStream_t stream) {
  const float* x      = (const float*)d_in[0];
  const float* td     = (const float*)d_in[1];
  const int*   labels = (const int*)d_in[2];
  float*       out    = (float*)d_out;

  char* w = (char*)d_ws;
  float* d2   = (float*)w;                                   // N_PTS floats
  float* bmin = (float*)(w + (size_t)N_PTS * sizeof(float)); // NBLK floats
  int*   cnt  = (int*)(bmin + NBLK);                         // 1 int
  int*   done = cnt + 1;                                     // 1 int
  int*   cand = done + 1;                                    // CAP ints

  k_dist<<<NBLK, TPB, 0, stream>>>(x, td, d2, bmin, cnt, done);
  k_rest<<<NBLK, TPB, 0, stream>>>(bmin, d2, labels, cnt, done, cand, out);
}

// Round 8
// 234.469 us; speedup vs baseline: 1.0877x; 1.0877x over previous
//
#include <hip/hip_runtime.h>

#define N_PTS   2000000
#define DIM     128
#define KSEL    15
#define TPB     256
#define NBLK    2048
#define NWAVE   (NBLK * (TPB / 64))     // 8192 waves
#define RSTRIDE (NWAVE * 2)             // 16384 rows per sweep step (8MB window)
#define NBLK3   2048
#define CAP     32768
#define FBIG    3.4028235e38f
#define IBIG    0x7fffffff

typedef float v4f __attribute__((ext_vector_type(4)));

// ---------------------------------------------------------------------------
// Kernel 1: distances. 32 lanes per row: lane l owns float4 at (l&31)*16B,
// wave halves take rows base / base+1 -> every global_load_dwordx4 covers
// exactly 1KB CONTIGUOUS (the fill/copy-bench pattern that hits 6.3+ TB/s,
// vs the 64B-granule 512B-stride scatter of previous rounds at 4.7 TB/s).
// Reduce = 5 shfl_xor within the 32-lane half (masks <32 never cross halves).
// Grid-stride sweep; all 8192 waves share one contiguous 8MB window.
// ---------------------------------------------------------------------------
__global__ __launch_bounds__(TPB) void k_dist(const float* __restrict__ x,
                                              const float* __restrict__ td,
                                              float* __restrict__ d2out,
                                              float* __restrict__ bmin) {
  const int tid = threadIdx.x;
  const int l32 = tid & 31;                         // lane within half-wave
  const int h   = (tid >> 5) & 1;                   // which row of the pair
  const int gw  = blockIdx.x * (TPB / 64) + (tid >> 6);  // global wave id

  const v4f* x4 = (const v4f*)x;
  const v4f xv = x4[l32];
  float xsq = xv.x * xv.x + xv.y * xv.y + xv.z * xv.z + xv.w * xv.w;
#pragma unroll
  for (int m = 1; m < 32; m <<= 1) xsq += __shfl_xor(xsq, m);

  float mymin = FBIG;
#pragma unroll 4
  for (int base = gw * 2; base < N_PTS; base += RSTRIDE) {
    const int row = base + h;                       // N_PTS even -> in range
    const v4f tv = *(const v4f*)(td + (size_t)row * DIM + l32 * 4);

    float att, atx;
    att = tv.x * tv.x;              atx = tv.x * xv.x;
    att = fmaf(tv.y, tv.y, att);    atx = fmaf(tv.y, xv.y, atx);
    att = fmaf(tv.z, tv.z, att);    atx = fmaf(tv.z, xv.z, atx);
    att = fmaf(tv.w, tv.w, att);    atx = fmaf(tv.w, xv.w, atx);
    float s = fmaf(-2.f, atx, att);
#pragma unroll
    for (int m = 1; m < 32; m <<= 1) s += __shfl_xor(s, m);   // half-wave sum
    float d2 = fmaxf(s + xsq, 0.f);
    if (l32 == 0) d2out[row] = d2;
    mymin = fminf(mymin, d2);
  }

  __shared__ float smin[TPB];
  smin[tid] = mymin;
  __syncthreads();
  for (int s = TPB / 2; s > 0; s >>= 1) {
    if (tid < s) smin[tid] = fminf(smin[tid], smin[tid + s]);
    __syncthreads();
  }
  if (tid == 0) bmin[blockIdx.x] = smin[0];
}

// ---------------------------------------------------------------------------
// Kernel 2: T = 15th-smallest block-min. Single wave, static indexing only.
// Each block-min is a real point's d2, so count(d2<=T) >= 15 is guaranteed.
// ---------------------------------------------------------------------------
__global__ __launch_bounds__(64) void k_thresh(const float* __restrict__ bmin,
                                               float* __restrict__ thr,
                                               int* __restrict__ cnt) {
  const int lane = threadIdx.x;
  float lv[KSEL];
#pragma unroll
  for (int k = 0; k < KSEL; k++) lv[k] = FBIG;

  for (int i = lane; i < NBLK; i += 64) {          // 32 values per lane
    float v = bmin[i];
#pragma unroll
    for (int q = 0; q < KSEL; q++) {               // static bubble insert
      float mn = fminf(lv[q], v);
      v = fmaxf(lv[q], v);
      lv[q] = mn;
    }
  }

  float T = FBIG;
#pragma unroll 1
  for (int k = 0; k < KSEL; k++) {
    float bv = lv[0];
    int   bl = lane;
#pragma unroll
    for (int m = 1; m < 64; m <<= 1) {
      float ov = __shfl_xor(bv, m);
      int   ol = __shfl_xor(bl, m);
      if (ov < bv || (ov == bv && ol < bl)) { bv = ov; bl = ol; }
    }
    if (lane == bl) {                               // winner consumes head
#pragma unroll
      for (int q = 0; q < KSEL - 1; q++) lv[q] = lv[q + 1];
      lv[KSEL - 1] = FBIG;
    }
    T = bv;
  }
  if (lane == 0) { thr[0] = T; cnt[0] = 0; }
}

// ---------------------------------------------------------------------------
// Kernel 3: compact indices with d2 <= T.
// ---------------------------------------------------------------------------
__global__ __launch_bounds__(TPB) void k_compact(const float* __restrict__ d2,
                                                 const float* __restrict__ thr,
                                                 int* __restrict__ cnt,
                                                 int* __restrict__ cand) {
  const float T = thr[0];
  int i = blockIdx.x * TPB + threadIdx.x;
  const int stride = gridDim.x * TPB;
  for (; i < N_PTS; i += stride) {
    if (d2[i] <= T) {
      int p = atomicAdd(cnt, 1);
      if (p < CAP) cand[p] = i;
    }
  }
}

// ---------------------------------------------------------------------------
// Kernel 4: exact top-15 over candidates ordered by (d2, index) — lowest
// index wins ties, matching lax.top_k. Vote with strict >, ties to the
// smallest class (matching jnp.argmax). All static indexing.
// ---------------------------------------------------------------------------
__global__ __launch_bounds__(64) void k_final(const float* __restrict__ d2,
                                              const int* __restrict__ cnt,
                                              const int* __restrict__ cand,
                                              const int* __restrict__ labels,
                                              float* __restrict__ out) {
  const int lane = threadIdx.x;
  int n = cnt[0];
  if (n > CAP) n = CAP;

  float lv[KSEL]; int li[KSEL];
#pragma unroll
  for (int k = 0; k < KSEL; k++) { lv[k] = FBIG; li[k] = IBIG; }

  for (int cdx = lane; cdx < n; cdx += 64) {
    int vi = cand[cdx];
    float v = d2[vi];
#pragma unroll
    for (int q = 0; q < KSEL; q++) {               // static pair bubble insert
      bool less = (v < lv[q]) || (v == lv[q] && vi < li[q]);
      float tv = less ? lv[q] : v;  int ti = less ? li[q] : vi;
      float nv = less ? v : lv[q];  int ni = less ? vi : li[q];
      lv[q] = nv; li[q] = ni;
      v = tv; vi = ti;
    }
  }

  int c0 = 0, c1 = 0, c2 = 0;
#pragma unroll 1
  for (int k = 0; k < KSEL; k++) {
    float bv = lv[0]; int bi = li[0]; int bl = lane;
#pragma unroll
    for (int m = 1; m < 64; m <<= 1) {
      float ov = __shfl_xor(bv, m);
      int   oi = __shfl_xor(bi, m);
      int   ol = __shfl_xor(bl, m);
      if (ov < bv || (ov == bv && (oi < bi || (oi == bi && ol < bl)))) {
        bv = ov; bi = oi; bl = ol;
      }
    }
    if (lane == bl) {                               // winner consumes head
#pragma unroll
      for (int q = 0; q < KSEL - 1; q++) { lv[q] = lv[q + 1]; li[q] = li[q + 1]; }
      lv[KSEL - 1] = FBIG; li[KSEL - 1] = IBIG;
    }
    if (lane == 0 && bi >= 0 && bi < N_PTS) {
      int lb = labels[bi];
      if (lb == 0) c0++; else if (lb == 1) c1++; else c2++;
    }
  }
  if (lane == 0) {
    int best = 0, bc = c0;
    if (c1 > bc) { best = 1; bc = c1; }
    if (c2 > bc) { best = 2; }
    out[0] = (float)best;
  }
}

extern "C" void kernel_launch(void* const* d_in, const int* in_sizes, int n_in,
                              void* d_out, int out_size, void* d_ws, size_t ws_size,
                              hipStream_t stream) {
  const float* x      = (const float*)d_in[0];
  const float* td     = (const float*)d_in[1];
  const int*   labels = (const int*)d_in[2];
  float*       out    = (float*)d_out;

  char* w = (char*)d_ws;
  float* d2   = (float*)w;                                   // N_PTS floats
  float* bmin = (float*)(w + (size_t)N_PTS * sizeof(float)); // NBLK floats
  float* thr  = bmin + NBLK;                                 // 1 float
  int*   cnt  = (int*)(thr + 1);                             // 1 int
  int*   cand = cnt + 1;                                     // CAP ints

  k_dist   <<<NBLK, TPB, 0, stream>>>(x, td, d2, bmin);
  k_thresh <<<1,    64,  0, stream>>>(bmin, thr, cnt);
  k_compact<<<NBLK3, TPB, 0, stream>>>(d2, thr, cnt, cand);
  k_final  <<<1,    64,  0, stream>>>(d2, cnt, cand, labels, out);
}